// Round 1
// baseline (2446.146 us; speedup 1.0000x reference)
//
#include <hip/hip_runtime.h>
#include <math.h>

// ---- problem constants ----
// L=2 B=2 S=1024 D=2048 H=16 HD=128 SKV=1024 V=16384
#define DM   2048
#define SEQ  1024
#define NB   2
#define NH   16
#define HD   128
#define NKV  2048    // 2*SKV concatenated keys
#define VOC  16384
#define TDQ  6144    // 3*D
#define FFD  8192    // 4*D

typedef __bf16 bf16x8 __attribute__((ext_vector_type(8)));
typedef float  f32x4  __attribute__((ext_vector_type(4)));

__device__ __forceinline__ unsigned short f2b(float f) {
    unsigned u = __builtin_bit_cast(unsigned, f);
    u += 0x7fffu + ((u >> 16) & 1u);   // RNE
    return (unsigned short)(u >> 16);
}
__device__ __forceinline__ float b2f(unsigned short u) {
    return __builtin_bit_cast(float, (unsigned)u << 16);
}

// ============================ positional encoding ============================
// xw = x + PE ; one float4 per thread
__global__ __launch_bounds__(256) void pe_kernel(const float* __restrict__ x,
                                                 const int* __restrict__ cp,
                                                 float* __restrict__ xw) {
    int idx  = blockIdx.x * 256 + threadIdx.x;        // float4 index
    int base = idx * 4;
    int d = base & (DM - 1);
    int s = (base >> 11) & (SEQ - 1);
    float pos = (float)(cp[0] + s);
    const float lf = -(9.210340371976184f / (float)DM);  // -ln(10000)/D
    int i0 = d >> 1;
    float f0 = __expf(lf * (float)(2 * i0));
    float f1 = __expf(lf * (float)(2 * (i0 + 1)));
    float a0 = pos * f0, a1 = pos * f1;
    float4 v = ((const float4*)x)[idx];
    v.x += sinf(a0); v.y += cosf(a0);
    v.z += sinf(a1); v.w += cosf(a1);
    ((float4*)xw)[idx] = v;
}

// ================================ layernorm =================================
// one block per row; writes bf16 row
__global__ __launch_bounds__(256) void ln_kernel(const float* __restrict__ x,
                                                 const float* __restrict__ w,
                                                 const float* __restrict__ bias,
                                                 unsigned short* __restrict__ xn) {
    int row = blockIdx.x, t = threadIdx.x;
    const float* xr = x + (size_t)row * DM;
    float4 a  = ((const float4*)xr)[2 * t];
    float4 b4 = ((const float4*)xr)[2 * t + 1];
    float s  = a.x + a.y + a.z + a.w + b4.x + b4.y + b4.z + b4.w;
    float s2 = a.x*a.x + a.y*a.y + a.z*a.z + a.w*a.w +
               b4.x*b4.x + b4.y*b4.y + b4.z*b4.z + b4.w*b4.w;
#pragma unroll
    for (int off = 32; off; off >>= 1) {
        s  += __shfl_down(s,  off);
        s2 += __shfl_down(s2, off);
    }
    __shared__ float red[8];
    int wv = t >> 6;
    if ((t & 63) == 0) { red[wv] = s; red[4 + wv] = s2; }
    __syncthreads();
    s  = red[0] + red[1] + red[2] + red[3];
    s2 = red[4] + red[5] + red[6] + red[7];
    float mean = s * (1.0f / DM);
    float var  = s2 * (1.0f / DM) - mean * mean;
    float rstd = rsqrtf(var + 1e-5f);
    int d = t * 8;
    float4 w0 = ((const float4*)(w + d))[0],    w1 = ((const float4*)(w + d))[1];
    float4 p0 = ((const float4*)(bias + d))[0], p1 = ((const float4*)(bias + d))[1];
    ushort4 u0, u1;
    u0.x = f2b((a.x - mean) * rstd * w0.x + p0.x);
    u0.y = f2b((a.y - mean) * rstd * w0.y + p0.y);
    u0.z = f2b((a.z - mean) * rstd * w0.z + p0.z);
    u0.w = f2b((a.w - mean) * rstd * w0.w + p0.w);
    u1.x = f2b((b4.x - mean) * rstd * w1.x + p1.x);
    u1.y = f2b((b4.y - mean) * rstd * w1.y + p1.y);
    u1.z = f2b((b4.z - mean) * rstd * w1.z + p1.z);
    u1.w = f2b((b4.w - mean) * rstd * w1.w + p1.w);
    *(ushort4*)(xn + (size_t)row * DM + d)     = u0;
    *(ushort4*)(xn + (size_t)row * DM + d + 4) = u1;
}

// ================================== GEMM ====================================
// C[M,N] = A[M,K](bf16) @ W[N,K](f32, split rows res|off)^T
// 128x128 tile, BK=32, 4 waves (2x2), each wave 4x4 16x16 tiles.
// mode 0: store bf16   1: exact-gelu -> bf16   2: resid + C -> f32   3: f32
__global__ __launch_bounds__(256) void gemm_kernel(
    const unsigned short* __restrict__ A,
    const float* __restrict__ Wres, const float* __restrict__ Woff, int nsplit,
    int K, int N,
    float* __restrict__ fout, unsigned short* __restrict__ bout,
    const float* __restrict__ resid, int mode) {
    __shared__ __attribute__((aligned(16))) unsigned short As[128 * 32];
    __shared__ __attribute__((aligned(16))) unsigned short Bs[128 * 32];
    int t = threadIdx.x;
    int n0 = blockIdx.x * 128, m0 = blockIdx.y * 128;
    const float* wb = (n0 < nsplit) ? (Wres + (size_t)n0 * K)
                                    : (Woff + (size_t)(n0 - nsplit) * K);
    int wv = t >> 6, lane = t & 63, ln = lane & 15, q = lane >> 4;
    int wm = (wv >> 1) * 64, wn = (wv & 1) * 64;
    int arow = t >> 2, aseg = t & 3;
    int brow = t >> 3, bseg = t & 7;
    f32x4 acc[4][4] = {};
    for (int k0 = 0; k0 < K; k0 += 32) {
        __syncthreads();
#pragma unroll
        for (int p = 0; p < 2; p++) {  // A: bf16 copy
            int row = arow + p * 64;
            *(uint4*)(As + row * 32 + aseg * 8) =
                *(const uint4*)(A + (size_t)(m0 + row) * K + k0 + aseg * 8);
        }
#pragma unroll
        for (int p = 0; p < 4; p++) {  // W: f32 -> bf16
            int row = brow + p * 32;
            float4 v = *(const float4*)(wb + (size_t)row * K + k0 + bseg * 4);
            ushort4 us; us.x = f2b(v.x); us.y = f2b(v.y); us.z = f2b(v.z); us.w = f2b(v.w);
            *(ushort4*)(Bs + row * 32 + bseg * 4) = us;
        }
        __syncthreads();
        bf16x8 af[4], bfr[4];
#pragma unroll
        for (int i = 0; i < 4; i++)
            af[i] = *(const bf16x8*)(As + (wm + i * 16 + ln) * 32 + q * 8);
#pragma unroll
        for (int i = 0; i < 4; i++)
            bfr[i] = *(const bf16x8*)(Bs + (wn + i * 16 + ln) * 32 + q * 8);
#pragma unroll
        for (int i = 0; i < 4; i++)
#pragma unroll
            for (int j = 0; j < 4; j++)
                acc[i][j] = __builtin_amdgcn_mfma_f32_16x16x32_bf16(
                    af[i], bfr[j], acc[i][j], 0, 0, 0);
    }
#pragma unroll
    for (int i = 0; i < 4; i++)
#pragma unroll
        for (int j = 0; j < 4; j++)
#pragma unroll
            for (int r = 0; r < 4; r++) {
                int row = m0 + wm + i * 16 + q * 4 + r;
                int col = n0 + wn + j * 16 + ln;
                size_t off = (size_t)row * N + col;
                float v = acc[i][j][r];
                if (mode == 0) {
                    bout[off] = f2b(v);
                } else if (mode == 1) {
                    float g = 0.5f * v * (1.0f + erff(v * 0.7071067811865476f));
                    bout[off] = f2b(g);
                } else if (mode == 2) {
                    fout[off] = resid[off] + v;
                } else {
                    fout[off] = v;
                }
            }
}

// ========================= V transpose (per layer) ==========================
// vt[b*16+h][d][kk] (bf16) = concat(v_res, v_scr)[kk][d], patch kk==2047 from qkv
__global__ __launch_bounds__(256) void vtrans_kernel(
    const float* __restrict__ v_res, const float* __restrict__ v_off,
    const unsigned short* __restrict__ qkv, unsigned short* __restrict__ vt,
    int layer) {
    __shared__ float tile[64 * 65];
    int t = threadIdx.x;
    int kt = blockIdx.x;           // key tile (64 wide)
    int dt = blockIdx.y;           // d tile (64 wide)
    int bh = blockIdx.z;
    int b = bh >> 4, h = bh & 15;
    size_t vbase = (((size_t)layer * NB + b) * NH + h) * 1024 * HD;
#pragma unroll
    for (int p = 0; p < 4; p++) {
        int f = t + 256 * p;
        int row = f >> 4, sg = f & 15;
        int kk = kt * 64 + row;
        int d = dt * 64 + sg * 4;
        float4 v;
        if (kk < 1024)
            v = *(const float4*)(v_res + vbase + (size_t)kk * HD + d);
        else if (kk < 2047)
            v = *(const float4*)(v_off + vbase + (size_t)(kk - 1024) * HD + d);
        else {
            const unsigned short* src =
                qkv + (size_t)(b * SEQ + (SEQ - 1)) * TDQ + h * 384 + 256 + d;
            v = make_float4(b2f(src[0]), b2f(src[1]), b2f(src[2]), b2f(src[3]));
        }
        tile[row * 65 + sg * 4 + 0] = v.x;
        tile[row * 65 + sg * 4 + 1] = v.y;
        tile[row * 65 + sg * 4 + 2] = v.z;
        tile[row * 65 + sg * 4 + 3] = v.w;
    }
    __syncthreads();
    int dd = t & 63, sg = t >> 6;   // sg in 0..3, 16 cols each
    unsigned short* dst = vt + ((size_t)bh * HD + dt * 64 + dd) * NKV + kt * 64 + sg * 16;
#pragma unroll
    for (int c4 = 0; c4 < 4; c4++) {
        ushort4 o;
        o.x = f2b(tile[(sg * 16 + c4 * 4 + 0) * 65 + dd]);
        o.y = f2b(tile[(sg * 16 + c4 * 4 + 1) * 65 + dd]);
        o.z = f2b(tile[(sg * 16 + c4 * 4 + 2) * 65 + dd]);
        o.w = f2b(tile[(sg * 16 + c4 * 4 + 3) * 65 + dd]);
        *(ushort4*)(dst + c4 * 4) = o;
    }
}

// ============================ flash attention ===============================
// 64-query tile / block; 4 waves x 16 query rows; online softmax; x += O
__global__ __launch_bounds__(256) void attn_kernel(
    const unsigned short* __restrict__ qkv,
    const float* __restrict__ k_res, const float* __restrict__ k_off,
    const unsigned short* __restrict__ vt,
    float* __restrict__ x, int layer) {
    __shared__ __attribute__((aligned(16))) unsigned short Qs[64 * 128];
    __shared__ __attribute__((aligned(16))) unsigned short Ks[64 * 128];
    __shared__ __attribute__((aligned(16))) unsigned short Vts[128 * 64];
    __shared__ __attribute__((aligned(16))) unsigned short Ps[4][16 * 64];
    int t = threadIdx.x;
    int q0 = blockIdx.x * 64, h = blockIdx.y, b = blockIdx.z;
    int wv = t >> 6, lane = t & 63, ln = lane & 15, q = lane >> 4;
    // stage Q (bf16 copy from qkv)
    {
        int row = t >> 4, sg = t & 15;
#pragma unroll
        for (int p = 0; p < 4; p++) {
            int r2 = row + 16 * p;
            *(uint4*)(Qs + r2 * 128 + sg * 8) =
                *(const uint4*)(qkv + (size_t)(b * SEQ + q0 + r2) * TDQ + h * 384 + sg * 8);
        }
    }
    f32x4 oacc[8] = {};
    float mrow[4] = {-1e30f, -1e30f, -1e30f, -1e30f};
    float lrow[4] = {};
    size_t kvbase = (((size_t)layer * NB + b) * NH + h) * 1024 * HD;
    const unsigned short* vtb = vt + ((size_t)(b * NH + h) * HD) * NKV;
    for (int kc = 0; kc < 32; kc++) {
        __syncthreads();
        // stage K chunk (f32 -> bf16; patch row 2047 from qkv)
        {
            int row = t >> 5, sg = t & 31;
#pragma unroll
            for (int p = 0; p < 8; p++) {
                int r2 = row + 8 * p;
                int kk = kc * 64 + r2;
                ushort4 us;
                if (kk < 2047) {
                    const float* src = (kk < 1024)
                        ? (k_res + kvbase + (size_t)kk * HD + sg * 4)
                        : (k_off + kvbase + (size_t)(kk - 1024) * HD + sg * 4);
                    float4 v = *(const float4*)src;
                    us.x = f2b(v.x); us.y = f2b(v.y); us.z = f2b(v.z); us.w = f2b(v.w);
                } else {
                    us = *(const ushort4*)(qkv + (size_t)(b * SEQ + (SEQ - 1)) * TDQ +
                                           h * 384 + 128 + sg * 4);
                }
                *(ushort4*)(Ks + r2 * 128 + sg * 4) = us;
            }
        }
        // stage Vt chunk (bf16 copy)
        {
            int row = t >> 3, sg = t & 7;
#pragma unroll
            for (int p = 0; p < 4; p++) {
                int r2 = row + 32 * p;
                *(uint4*)(Vts + r2 * 64 + sg * 8) =
                    *(const uint4*)(vtb + (size_t)r2 * NKV + kc * 64 + sg * 8);
            }
        }
        __syncthreads();
        // S = Q @ K^T (16 queries x 64 keys per wave)
        f32x4 st[4] = {};
#pragma unroll
        for (int ks = 0; ks < 4; ks++) {
            bf16x8 af = *(const bf16x8*)(Qs + (wv * 16 + ln) * 128 + ks * 32 + q * 8);
#pragma unroll
            for (int nt = 0; nt < 4; nt++) {
                bf16x8 bfr = *(const bf16x8*)(Ks + (nt * 16 + ln) * 128 + ks * 32 + q * 8);
                st[nt] = __builtin_amdgcn_mfma_f32_16x16x32_bf16(af, bfr, st[nt], 0, 0, 0);
            }
        }
        const float sc = 0.08838834764831845f;  // 1/sqrt(128)
#pragma unroll
        for (int nt = 0; nt < 4; nt++)
#pragma unroll
            for (int r = 0; r < 4; r++) st[nt][r] *= sc;
        float alpha[4];
#pragma unroll
        for (int r = 0; r < 4; r++) {
            float m1 = fmaxf(fmaxf(st[0][r], st[1][r]), fmaxf(st[2][r], st[3][r]));
#pragma unroll
            for (int off = 8; off; off >>= 1) m1 = fmaxf(m1, __shfl_xor(m1, off));
            float mn = fmaxf(mrow[r], m1);
            float al = __expf(mrow[r] - mn);
            mrow[r] = mn;
            float s = 0.0f;
#pragma unroll
            for (int nt = 0; nt < 4; nt++) {
                float p = __expf(st[nt][r] - mn);
                st[nt][r] = p;
                s += p;
            }
#pragma unroll
            for (int off = 8; off; off >>= 1) s += __shfl_xor(s, off);
            lrow[r] = lrow[r] * al + s;
            alpha[r] = al;
        }
#pragma unroll
        for (int ot = 0; ot < 8; ot++)
#pragma unroll
            for (int r = 0; r < 4; r++) oacc[ot][r] *= alpha[r];
        // P: C-layout -> LDS (A-layout read)
#pragma unroll
        for (int nt = 0; nt < 4; nt++)
#pragma unroll
            for (int r = 0; r < 4; r++)
                Ps[wv][(q * 4 + r) * 64 + nt * 16 + ln] = f2b(st[nt][r]);
        // O += P @ V
#pragma unroll
        for (int ks = 0; ks < 2; ks++) {
            bf16x8 af = *(const bf16x8*)(&Ps[wv][0] + ln * 64 + ks * 32 + q * 8);
#pragma unroll
            for (int ot = 0; ot < 8; ot++) {
                bf16x8 bfr = *(const bf16x8*)(Vts + (ot * 16 + ln) * 64 + ks * 32 + q * 8);
                oacc[ot] = __builtin_amdgcn_mfma_f32_16x16x32_bf16(af, bfr, oacc[ot], 0, 0, 0);
            }
        }
    }
    float inv[4];
#pragma unroll
    for (int r = 0; r < 4; r++) inv[r] = 1.0f / lrow[r];
#pragma unroll
    for (int ot = 0; ot < 8; ot++)
#pragma unroll
        for (int r = 0; r < 4; r++) {
            int s_idx = q0 + wv * 16 + q * 4 + r;
            int d = ot * 16 + ln;
            size_t off = ((size_t)b * SEQ + s_idx) * DM + h * HD + d;
            x[off] += oacc[ot][r] * inv[r];
        }
}

// ============================== final softmax ===============================
// in-place on d_out; one block per row of 16384
__global__ __launch_bounds__(256) void softmax_kernel(float* __restrict__ io) {
    int row = blockIdx.x, t = threadIdx.x;
    float4* p = (float4*)(io + (size_t)row * VOC);
    float4 v[16];
    float mx = -1e30f;
#pragma unroll
    for (int i = 0; i < 16; i++) {
        v[i] = p[t + 256 * i];
        mx = fmaxf(mx, fmaxf(fmaxf(v[i].x, v[i].y), fmaxf(v[i].z, v[i].w)));
    }
#pragma unroll
    for (int off = 32; off; off >>= 1) mx = fmaxf(mx, __shfl_xor(mx, off));
    __shared__ float red[8];
    int wv = t >> 6;
    if ((t & 63) == 0) red[wv] = mx;
    __syncthreads();
    mx = fmaxf(fmaxf(red[0], red[1]), fmaxf(red[2], red[3]));
    float sum = 0.0f;
#pragma unroll
    for (int i = 0; i < 16; i++) {
        v[i].x = __expf(v[i].x - mx); v[i].y = __expf(v[i].y - mx);
        v[i].z = __expf(v[i].z - mx); v[i].w = __expf(v[i].w - mx);
        sum += v[i].x + v[i].y + v[i].z + v[i].w;
    }
#pragma unroll
    for (int off = 32; off; off >>= 1) sum += __shfl_xor(sum, off);
    if ((t & 63) == 0) red[4 + wv] = sum;
    __syncthreads();
    sum = red[4] + red[5] + red[6] + red[7];
    float inv = 1.0f / sum;
#pragma unroll
    for (int i = 0; i < 16; i++) {
        v[i].x *= inv; v[i].y *= inv; v[i].z *= inv; v[i].w *= inv;
        p[t + 256 * i] = v[i];
    }
}

// ================================= launch ===================================
extern "C" void kernel_launch(void* const* d_in, const int* in_sizes, int n_in,
                              void* d_out, int out_size, void* d_ws, size_t ws_size,
                              hipStream_t stream) {
    (void)in_sizes; (void)n_in; (void)out_size; (void)ws_size;
    const float* x_in    = (const float*)d_in[0];
    const float* ln_w    = (const float*)d_in[1];
    const float* ln_b    = (const float*)d_in[2];
    const float* qkv_res = (const float*)d_in[3];
    const float* qkv_off = (const float*)d_in[4];
    const float* k_res   = (const float*)d_in[5];
    const float* v_res   = (const float*)d_in[6];
    const float* k_off   = (const float*)d_in[7];
    const float* v_off   = (const float*)d_in[8];
    const float* f1_res  = (const float*)d_in[9];
    const float* f1_off  = (const float*)d_in[10];
    const float* f2_res  = (const float*)d_in[11];
    const float* f2_off  = (const float*)d_in[12];
    const float* o_res   = (const float*)d_in[13];
    const float* o_off   = (const float*)d_in[14];
    const int*   cp      = (const int*)d_in[15];
    float* out = (float*)d_out;
    char*  ws  = (char*)d_ws;

    // ws layout (bytes): x 0..16M | xn 16M..25M | qkv 25M..50M | h/vt 50M..84M
    float*          xw   = (float*)(ws);
    unsigned short* xn   = (unsigned short*)(ws + 16777216);
    unsigned short* qkvb = (unsigned short*)(ws + 25165824);
    unsigned short* hb   = (unsigned short*)(ws + 50331648);
    unsigned short* vt   = (unsigned short*)(ws + 50331648);  // disjoint lifetime vs hb

    pe_kernel<<<4096, 256, 0, stream>>>(x_in, cp, xw);
    for (int l = 0; l < 2; l++) {
        ln_kernel<<<2048, 256, 0, stream>>>(xw, ln_w, ln_b, xn);
        gemm_kernel<<<dim3(48, 16), 256, 0, stream>>>(
            xn, qkv_res + (size_t)l * 3072 * 2048, qkv_off + (size_t)l * 3072 * 2048,
            3072, 2048, TDQ, nullptr, qkvb, nullptr, 0);
        vtrans_kernel<<<dim3(32, 2, 32), 256, 0, stream>>>(v_res, v_off, qkvb, vt, l);
        attn_kernel<<<dim3(16, 16, 2), 256, 0, stream>>>(qkvb, k_res, k_off, vt, xw, l);
        ln_kernel<<<2048, 256, 0, stream>>>(xw, ln_w, ln_b, xn);
        gemm_kernel<<<dim3(64, 16), 256, 0, stream>>>(
            xn, f1_res + (size_t)l * 4096 * 2048, f1_off + (size_t)l * 4096 * 2048,
            4096, 2048, FFD, nullptr, hb, nullptr, 1);
        gemm_kernel<<<dim3(16, 16), 256, 0, stream>>>(
            hb, f2_res + (size_t)l * 1024 * 8192, f2_off + (size_t)l * 1024 * 8192,
            1024, 8192, DM, xw, nullptr, xw, 2);
    }
    ln_kernel<<<2048, 256, 0, stream>>>(xw, ln_w, ln_b, xn);
    gemm_kernel<<<dim3(128, 16), 256, 0, stream>>>(
        xn, o_res, o_off, 8192, 2048, VOC, out, nullptr, nullptr, 3);
    softmax_kernel<<<2048, 256, 0, stream>>>(out);
}

// Round 2
// 1838.074 us; speedup vs baseline: 1.3308x; 1.3308x over previous
//
#include <hip/hip_runtime.h>
#include <math.h>

// ---- problem constants ----
// L=2 B=2 S=1024 D=2048 H=16 HD=128 SKV=1024 V=16384
#define DM   2048
#define SEQ  1024
#define NB   2
#define NH   16
#define HD   128
#define NKV  2048    // 2*SKV concatenated keys
#define VOC  16384
#define TDQ  6144    // 3*D
#define FFD  8192    // 4*D

typedef __bf16 bf16x8 __attribute__((ext_vector_type(8)));
typedef float  f32x4  __attribute__((ext_vector_type(4)));
typedef unsigned short us8 __attribute__((ext_vector_type(8)));

__device__ __forceinline__ unsigned short f2b(float f) {
    unsigned u = __builtin_bit_cast(unsigned, f);
    u += 0x7fffu + ((u >> 16) & 1u);   // RNE
    return (unsigned short)(u >> 16);
}
__device__ __forceinline__ float b2f(unsigned short u) {
    return __builtin_bit_cast(float, (unsigned)u << 16);
}
// async global->LDS, 16B per lane; LDS dest = wave-uniform base + lane*16
__device__ __forceinline__ void glds16(const void* g, void* l) {
    __builtin_amdgcn_global_load_lds(
        (const __attribute__((address_space(1))) unsigned int*)g,
        (__attribute__((address_space(3))) unsigned int*)l, 16, 0, 0);
}

// ============================ positional encoding ============================
__global__ __launch_bounds__(256) void pe_kernel(const float* __restrict__ x,
                                                 const int* __restrict__ cp,
                                                 float* __restrict__ xw) {
    int idx  = blockIdx.x * 256 + threadIdx.x;        // float4 index
    int base = idx * 4;
    int d = base & (DM - 1);
    int s = (base >> 11) & (SEQ - 1);
    float pos = (float)(cp[0] + s);
    const float lf = -(9.210340371976184f / (float)DM);  // -ln(10000)/D
    int i0 = d >> 1;
    float f0 = __expf(lf * (float)(2 * i0));
    float f1 = __expf(lf * (float)(2 * (i0 + 1)));
    float a0 = pos * f0, a1 = pos * f1;
    float4 v = ((const float4*)x)[idx];
    v.x += sinf(a0); v.y += cosf(a0);
    v.z += sinf(a1); v.w += cosf(a1);
    ((float4*)xw)[idx] = v;
}

// ================================ layernorm =================================
__global__ __launch_bounds__(256) void ln_kernel(const float* __restrict__ x,
                                                 const float* __restrict__ w,
                                                 const float* __restrict__ bias,
                                                 unsigned short* __restrict__ xn) {
    int row = blockIdx.x, t = threadIdx.x;
    const float* xr = x + (size_t)row * DM;
    float4 a  = ((const float4*)xr)[2 * t];
    float4 b4 = ((const float4*)xr)[2 * t + 1];
    float s  = a.x + a.y + a.z + a.w + b4.x + b4.y + b4.z + b4.w;
    float s2 = a.x*a.x + a.y*a.y + a.z*a.z + a.w*a.w +
               b4.x*b4.x + b4.y*b4.y + b4.z*b4.z + b4.w*b4.w;
#pragma unroll
    for (int off = 32; off; off >>= 1) {
        s  += __shfl_down(s,  off);
        s2 += __shfl_down(s2, off);
    }
    __shared__ float red[8];
    int wv = t >> 6;
    if ((t & 63) == 0) { red[wv] = s; red[4 + wv] = s2; }
    __syncthreads();
    s  = red[0] + red[1] + red[2] + red[3];
    s2 = red[4] + red[5] + red[6] + red[7];
    float mean = s * (1.0f / DM);
    float var  = s2 * (1.0f / DM) - mean * mean;
    float rstd = rsqrtf(var + 1e-5f);
    int d = t * 8;
    float4 w0 = ((const float4*)(w + d))[0],    w1 = ((const float4*)(w + d))[1];
    float4 p0 = ((const float4*)(bias + d))[0], p1 = ((const float4*)(bias + d))[1];
    us8 u;
    u[0] = f2b((a.x - mean) * rstd * w0.x + p0.x);
    u[1] = f2b((a.y - mean) * rstd * w0.y + p0.y);
    u[2] = f2b((a.z - mean) * rstd * w0.z + p0.z);
    u[3] = f2b((a.w - mean) * rstd * w0.w + p0.w);
    u[4] = f2b((b4.x - mean) * rstd * w1.x + p1.x);
    u[5] = f2b((b4.y - mean) * rstd * w1.y + p1.y);
    u[6] = f2b((b4.z - mean) * rstd * w1.z + p1.z);
    u[7] = f2b((b4.w - mean) * rstd * w1.w + p1.w);
    *(us8*)(xn + (size_t)row * DM + d) = u;
}

// ======================== weight convert (f32 -> bf16) ======================
// dst[ntot] = concat(res[nres], off[ntot-nres]) as bf16; 8 elems/thread
__global__ __launch_bounds__(256) void wconv_kernel(const float* __restrict__ res,
                                                    const float* __restrict__ off,
                                                    unsigned short* __restrict__ dst,
                                                    int nres) {
    int idx = (blockIdx.x * 256 + threadIdx.x) * 8;
    const float* src = (idx < nres) ? (res + idx) : (off + (idx - nres));
    float4 a = ((const float4*)src)[0];
    float4 b = ((const float4*)src)[1];
    us8 u;
    u[0] = f2b(a.x); u[1] = f2b(a.y); u[2] = f2b(a.z); u[3] = f2b(a.w);
    u[4] = f2b(b.x); u[5] = f2b(b.y); u[6] = f2b(b.z); u[7] = f2b(b.w);
    *(us8*)(dst + idx) = u;
}

// ================================== GEMM ====================================
// C[M,N] = A[M,K](bf16) @ W[N,K](bf16)^T ; 128x128 tile, BK=32, m97-style
// global_load_lds staging. blockIdx.z = K-split chunk (partials for mode 3).
// mode 0: store bf16   1: exact-gelu -> bf16   3: f32 store
__global__ __launch_bounds__(256) void gemm_kernel(
    const unsigned short* __restrict__ A, const unsigned short* __restrict__ W,
    int K, int N, int ldc,
    float* __restrict__ fout, unsigned short* __restrict__ bout, int mode) {
    __shared__ __attribute__((aligned(16))) unsigned short As[128 * 32];
    __shared__ __attribute__((aligned(16))) unsigned short Bs[128 * 32];
    int t = threadIdx.x;
    int n0 = blockIdx.x * 128, m0 = blockIdx.y * 128;
    int klen = K / (int)gridDim.z;
    int kbeg = blockIdx.z * klen;
    int wv = t >> 6, lane = t & 63, ln = lane & 15, q = lane >> 4;
    int wm = (wv >> 1) * 64, wn = (wv & 1) * 64;
    int l4 = lane >> 2, l4r = lane & 3;
    // wave wv stages rows [wv*32, wv*32+32) of As and Bs
    const unsigned short* Ag = A + (size_t)(m0 + wv * 32 + l4) * K + kbeg + l4r * 8;
    const unsigned short* Wg = W + (size_t)(n0 + wv * 32 + l4) * K + kbeg + l4r * 8;
    unsigned short* AsW = As + (wv * 32) * 32;
    unsigned short* BsW = Bs + (wv * 32) * 32;
    f32x4 acc[4][4] = {};
    for (int k0 = 0; k0 < klen; k0 += 32) {
        __syncthreads();
        glds16(Ag,          AsW);
        glds16(Ag + 16 * K, AsW + 16 * 32);
        glds16(Wg,          BsW);
        glds16(Wg + 16 * K, BsW + 16 * 32);
        Ag += 32; Wg += 32;
        __syncthreads();
        bf16x8 af[4], bfr[4];
#pragma unroll
        for (int i = 0; i < 4; i++)
            af[i] = *(const bf16x8*)(As + (wm + i * 16 + ln) * 32 + q * 8);
#pragma unroll
        for (int i = 0; i < 4; i++)
            bfr[i] = *(const bf16x8*)(Bs + (wn + i * 16 + ln) * 32 + q * 8);
#pragma unroll
        for (int i = 0; i < 4; i++)
#pragma unroll
            for (int j = 0; j < 4; j++)
                acc[i][j] = __builtin_amdgcn_mfma_f32_16x16x32_bf16(
                    af[i], bfr[j], acc[i][j], 0, 0, 0);
    }
    size_t zoff = (size_t)blockIdx.z * (size_t)gridDim.y * 128 * ldc;
#pragma unroll
    for (int i = 0; i < 4; i++)
#pragma unroll
        for (int j = 0; j < 4; j++)
#pragma unroll
            for (int r = 0; r < 4; r++) {
                int row = m0 + wm + i * 16 + q * 4 + r;
                int col = n0 + wn + j * 16 + ln;
                size_t off = (size_t)row * ldc + col;
                float v = acc[i][j][r];
                if (mode == 0) {
                    bout[off] = f2b(v);
                } else if (mode == 1) {
                    float g = 0.5f * v * (1.0f + erff(v * 0.7071067811865476f));
                    bout[off] = f2b(g);
                } else {
                    fout[zoff + off] = v;
                }
            }
}

// =================== FFN2 split-K reduce + residual add =====================
__global__ __launch_bounds__(256) void red_kernel(float* __restrict__ xw,
                                                  const float* __restrict__ p) {
    int i = blockIdx.x * 256 + threadIdx.x;   // float4 index
    const size_t STR = (size_t)DM * DM;       // 4,194,304 elems per partial
    float4 a = ((const float4*)p)[i];
    float4 b = ((const float4*)(p + STR))[i];
    float4 c = ((const float4*)(p + 2 * STR))[i];
    float4 d = ((const float4*)(p + 3 * STR))[i];
    float4 x = ((float4*)xw)[i];
    x.x += a.x + b.x + c.x + d.x;
    x.y += a.y + b.y + c.y + d.y;
    x.z += a.z + b.z + c.z + d.z;
    x.w += a.w + b.w + c.w + d.w;
    ((float4*)xw)[i] = x;
}

// ========================= V transpose (per layer) ==========================
// vt[b*16+h][d][kk] (bf16) = concat(v_res, v_scr)[kk][d], patch kk==2047
__global__ __launch_bounds__(256) void vtrans_kernel(
    const float* __restrict__ v_res, const float* __restrict__ v_off,
    const unsigned short* __restrict__ qkv, unsigned short* __restrict__ vt,
    int layer) {
    __shared__ float tile[64 * 65];
    int t = threadIdx.x;
    int kt = blockIdx.x;           // key tile (64 wide)
    int dt = blockIdx.y;           // d tile (64 wide)
    int bh = blockIdx.z;
    int b = bh >> 4, h = bh & 15;
    size_t vbase = (((size_t)layer * NB + b) * NH + h) * 1024 * HD;
#pragma unroll
    for (int p = 0; p < 4; p++) {
        int f = t + 256 * p;
        int row = f >> 4, sg = f & 15;
        int kk = kt * 64 + row;
        int d = dt * 64 + sg * 4;
        float4 v;
        if (kk < 1024)
            v = *(const float4*)(v_res + vbase + (size_t)kk * HD + d);
        else if (kk < 2047)
            v = *(const float4*)(v_off + vbase + (size_t)(kk - 1024) * HD + d);
        else {
            const unsigned short* src =
                qkv + (size_t)(b * SEQ + (SEQ - 1)) * TDQ + h * 384 + 256 + d;
            v = make_float4(b2f(src[0]), b2f(src[1]), b2f(src[2]), b2f(src[3]));
        }
        tile[row * 65 + sg * 4 + 0] = v.x;
        tile[row * 65 + sg * 4 + 1] = v.y;
        tile[row * 65 + sg * 4 + 2] = v.z;
        tile[row * 65 + sg * 4 + 3] = v.w;
    }
    __syncthreads();
    // write: 16B contiguous per thread along k
#pragma unroll
    for (int pass = 0; pass < 2; pass++) {
        int r = pass * 32 + (t >> 3);   // d within tile
        int sg = t & 7;                 // k segment (8 elems)
        us8 o;
#pragma unroll
        for (int j = 0; j < 8; j++) o[j] = f2b(tile[(sg * 8 + j) * 65 + r]);
        *(us8*)(vt + ((size_t)bh * HD + dt * 64 + r) * NKV + kt * 64 + sg * 8) = o;
    }
}

// ==================== K convert + patch + fold 1/sqrt(hd) ===================
// kb[b*16+h][kk][d] (bf16) = concat(k_res, k_scr)[kk][d] * scale
__global__ __launch_bounds__(256) void ktrans_kernel(
    const float* __restrict__ k_res, const float* __restrict__ k_off,
    const unsigned short* __restrict__ qkv, unsigned short* __restrict__ kb,
    int layer) {
    const float sc = 0.08838834764831845f;   // 1/sqrt(128)
    int idx = blockIdx.x * 256 + threadIdx.x;  // ushort8 unit
    int d = (idx & 15) * 8;
    int kk = (idx >> 4) & 2047;
    int bh = idx >> 15;
    int b = bh >> 4, h = bh & 15;
    size_t base = (((size_t)layer * NB + b) * NH + h) * 1024 * HD;
    float v[8];
    if (kk < 2047) {
        const float* src = (kk < 1024) ? (k_res + base + (size_t)kk * HD + d)
                                       : (k_off + base + (size_t)(kk - 1024) * HD + d);
        float4 a = ((const float4*)src)[0], c = ((const float4*)src)[1];
        v[0] = a.x; v[1] = a.y; v[2] = a.z; v[3] = a.w;
        v[4] = c.x; v[5] = c.y; v[6] = c.z; v[7] = c.w;
    } else {
        us8 u = *(const us8*)(qkv + (size_t)(b * SEQ + (SEQ - 1)) * TDQ + h * 384 + 128 + d);
#pragma unroll
        for (int j = 0; j < 8; j++) v[j] = b2f(u[j]);
    }
    us8 o;
#pragma unroll
    for (int j = 0; j < 8; j++) o[j] = f2b(v[j] * sc);
    *(us8*)(kb + ((size_t)bh * NKV + kk) * HD + d) = o;
}

// ============================ flash attention ===============================
// 64-query tile / block; Q in registers; glds staging; online softmax; x += O
__global__ __launch_bounds__(256) void attn_kernel(
    const unsigned short* __restrict__ qkv,
    const unsigned short* __restrict__ kb, const unsigned short* __restrict__ vt,
    float* __restrict__ x) {
    __shared__ __attribute__((aligned(16))) unsigned short Ks[64 * 128];
    __shared__ __attribute__((aligned(16))) unsigned short Vts[128 * 64];
    __shared__ __attribute__((aligned(16))) unsigned short Ps[4][16 * 64];
    int t = threadIdx.x;
    int q0 = blockIdx.x * 64, h = blockIdx.y, b = blockIdx.z;
    int wv = t >> 6, lane = t & 63, ln = lane & 15, q = lane >> 4;
    // Q fragments directly to registers (A-layout)
    bf16x8 qf[4];
    {
        const unsigned short* qsrc =
            qkv + (size_t)(b * SEQ + q0 + wv * 16 + ln) * TDQ + h * 384 + q * 8;
#pragma unroll
        for (int ks = 0; ks < 4; ks++) qf[ks] = *(const bf16x8*)(qsrc + ks * 32);
    }
    f32x4 oacc[8] = {};
    float mrow[4] = {-1e30f, -1e30f, -1e30f, -1e30f};
    float lrow[4] = {};
    const unsigned short* kbase = kb + (size_t)(b * NH + h) * NKV * HD;
    const unsigned short* vbase = vt + (size_t)(b * NH + h) * HD * NKV;
    for (int kc = 0; kc < 32; kc++) {
        __syncthreads();
        // K chunk: Ks[64][128]; wave stages rows [wv*16, wv*16+16), 4 calls
        {
            const unsigned short* kg =
                kbase + (size_t)(kc * 64 + wv * 16 + (lane >> 4)) * HD + (lane & 15) * 8;
            unsigned short* ld = Ks + (wv * 16) * 128;
#pragma unroll
            for (int p = 0; p < 4; p++)
                glds16(kg + (size_t)p * 4 * HD, ld + p * 4 * 128);
        }
        // V chunk: Vts[128][64]; wave stages rows [wv*32, wv*32+32), 4 calls
        {
            const unsigned short* vg =
                vbase + (size_t)(wv * 32 + (lane >> 3)) * NKV + kc * 64 + (lane & 7) * 8;
            unsigned short* ld = Vts + (wv * 32) * 64;
#pragma unroll
            for (int p = 0; p < 4; p++)
                glds16(vg + (size_t)p * 8 * NKV, ld + p * 8 * 64);
        }
        __syncthreads();
        // S = Q @ K^T (16 queries x 64 keys per wave); scale pre-folded into K
        f32x4 st[4] = {};
#pragma unroll
        for (int ks = 0; ks < 4; ks++) {
#pragma unroll
            for (int nt = 0; nt < 4; nt++) {
                bf16x8 bfr = *(const bf16x8*)(Ks + (nt * 16 + ln) * 128 + ks * 32 + q * 8);
                st[nt] = __builtin_amdgcn_mfma_f32_16x16x32_bf16(qf[ks], bfr, st[nt], 0, 0, 0);
            }
        }
        float alpha[4];
#pragma unroll
        for (int r = 0; r < 4; r++) {
            float m1 = fmaxf(fmaxf(st[0][r], st[1][r]), fmaxf(st[2][r], st[3][r]));
#pragma unroll
            for (int off = 8; off; off >>= 1) m1 = fmaxf(m1, __shfl_xor(m1, off));
            float mn = fmaxf(mrow[r], m1);
            float al = __expf(mrow[r] - mn);
            mrow[r] = mn;
            float s = 0.0f;
#pragma unroll
            for (int nt = 0; nt < 4; nt++) {
                float p = __expf(st[nt][r] - mn);
                st[nt][r] = p;
                s += p;
            }
#pragma unroll
            for (int off = 8; off; off >>= 1) s += __shfl_xor(s, off);
            lrow[r] = lrow[r] * al + s;
            alpha[r] = al;
        }
#pragma unroll
        for (int ot = 0; ot < 8; ot++)
#pragma unroll
            for (int r = 0; r < 4; r++) oacc[ot][r] *= alpha[r];
        // P: C-layout -> LDS (A-layout read)
#pragma unroll
        for (int nt = 0; nt < 4; nt++)
#pragma unroll
            for (int r = 0; r < 4; r++)
                Ps[wv][(q * 4 + r) * 64 + nt * 16 + ln] = f2b(st[nt][r]);
        // O += P @ V
#pragma unroll
        for (int ks = 0; ks < 2; ks++) {
            bf16x8 af = *(const bf16x8*)(&Ps[wv][0] + ln * 64 + ks * 32 + q * 8);
#pragma unroll
            for (int ot = 0; ot < 8; ot++) {
                bf16x8 bfr = *(const bf16x8*)(Vts + (ot * 16 + ln) * 64 + ks * 32 + q * 8);
                oacc[ot] = __builtin_amdgcn_mfma_f32_16x16x32_bf16(af, bfr, oacc[ot], 0, 0, 0);
            }
        }
    }
    float inv[4];
#pragma unroll
    for (int r = 0; r < 4; r++) inv[r] = 1.0f / lrow[r];
#pragma unroll
    for (int ot = 0; ot < 8; ot++)
#pragma unroll
        for (int r = 0; r < 4; r++) {
            int s_idx = q0 + wv * 16 + q * 4 + r;
            int d = ot * 16 + ln;
            size_t off = ((size_t)b * SEQ + s_idx) * DM + h * HD + d;
            x[off] += oacc[ot][r] * inv[r];
        }
}

// ============================== final softmax ===============================
__global__ __launch_bounds__(256) void softmax_kernel(float* __restrict__ io) {
    int row = blockIdx.x, t = threadIdx.x;
    float4* p = (float4*)(io + (size_t)row * VOC);
    float4 v[16];
    float mx = -1e30f;
#pragma unroll
    for (int i = 0; i < 16; i++) {
        v[i] = p[t + 256 * i];
        mx = fmaxf(mx, fmaxf(fmaxf(v[i].x, v[i].y), fmaxf(v[i].z, v[i].w)));
    }
#pragma unroll
    for (int off = 32; off; off >>= 1) mx = fmaxf(mx, __shfl_xor(mx, off));
    __shared__ float red[8];
    int wv = t >> 6;
    if ((t & 63) == 0) red[wv] = mx;
    __syncthreads();
    mx = fmaxf(fmaxf(red[0], red[1]), fmaxf(red[2], red[3]));
    float sum = 0.0f;
#pragma unroll
    for (int i = 0; i < 16; i++) {
        v[i].x = __expf(v[i].x - mx); v[i].y = __expf(v[i].y - mx);
        v[i].z = __expf(v[i].z - mx); v[i].w = __expf(v[i].w - mx);
        sum += v[i].x + v[i].y + v[i].z + v[i].w;
    }
#pragma unroll
    for (int off = 32; off; off >>= 1) sum += __shfl_xor(sum, off);
    if ((t & 63) == 0) red[4 + wv] = sum;
    __syncthreads();
    sum = red[4] + red[5] + red[6] + red[7];
    float inv = 1.0f / sum;
#pragma unroll
    for (int i = 0; i < 16; i++) {
        v[i].x *= inv; v[i].y *= inv; v[i].z *= inv; v[i].w *= inv;
        p[t + 256 * i] = v[i];
    }
}

// ================================= launch ===================================
extern "C" void kernel_launch(void* const* d_in, const int* in_sizes, int n_in,
                              void* d_out, int out_size, void* d_ws, size_t ws_size,
                              hipStream_t stream) {
    (void)in_sizes; (void)n_in; (void)out_size; (void)ws_size;
    const float* x_in    = (const float*)d_in[0];
    const float* ln_w    = (const float*)d_in[1];
    const float* ln_b    = (const float*)d_in[2];
    const float* qkv_res = (const float*)d_in[3];
    const float* qkv_off = (const float*)d_in[4];
    const float* k_res   = (const float*)d_in[5];
    const float* v_res   = (const float*)d_in[6];
    const float* k_off   = (const float*)d_in[7];
    const float* v_off   = (const float*)d_in[8];
    const float* f1_res  = (const float*)d_in[9];
    const float* f1_off  = (const float*)d_in[10];
    const float* f2_res  = (const float*)d_in[11];
    const float* f2_off  = (const float*)d_in[12];
    const float* o_res   = (const float*)d_in[13];
    const float* o_off   = (const float*)d_in[14];
    const int*   cp      = (const int*)d_in[15];
    float* out = (float*)d_out;
    char*  ws  = (char*)d_ws;

    // ws layout (bytes), total need = 117,440,512:
    //  xw   f32   0         .. 16,777,216
    //  xn   bf16  16,777,216 .. 25,165,824
    //  qkvb bf16  25,165,824 .. 50,331,648
    //  r1:  vt (16.78M) + kb (16.78M) | hb (33.55M)   50,331,648 .. 83,886,080
    //  wcv  bf16  83,886,080 .. 117,440,512  (weight panel, <=33.55M)
    float*          xw   = (float*)(ws);
    unsigned short* xn   = (unsigned short*)(ws + 16777216);
    unsigned short* qkvb = (unsigned short*)(ws + 25165824);
    unsigned short* vt   = (unsigned short*)(ws + 50331648);
    unsigned short* kb   = (unsigned short*)(ws + 67108864);
    unsigned short* hb   = (unsigned short*)(ws + 50331648);  // aliases vt+kb (disjoint lifetime)
    unsigned short* wcv  = (unsigned short*)(ws + 83886080);

    pe_kernel<<<4096, 256, 0, stream>>>(x_in, cp, xw);
    for (int l = 0; l < 2; l++) {
        ln_kernel<<<2048, 256, 0, stream>>>(xw, ln_w, ln_b, xn);
        // QKV
        wconv_kernel<<<6144, 256, 0, stream>>>(
            qkv_res + (size_t)l * 3072 * 2048, qkv_off + (size_t)l * 3072 * 2048,
            wcv, 3072 * 2048);
        gemm_kernel<<<dim3(48, 16, 1), 256, 0, stream>>>(
            xn, wcv, 2048, TDQ, TDQ, nullptr, qkvb, 0);
        // attention
        vtrans_kernel<<<dim3(32, 2, 32), 256, 0, stream>>>(v_res, v_off, qkvb, vt, l);
        ktrans_kernel<<<4096, 256, 0, stream>>>(k_res, k_off, qkvb, kb, l);
        attn_kernel<<<dim3(16, 16, 2), 256, 0, stream>>>(qkvb, kb, vt, xw);
        // FFN
        ln_kernel<<<2048, 256, 0, stream>>>(xw, ln_w, ln_b, xn);
        wconv_kernel<<<8192, 256, 0, stream>>>(
            f1_res + (size_t)l * 4096 * 2048, f1_off + (size_t)l * 4096 * 2048,
            wcv, 4096 * 2048);
        gemm_kernel<<<dim3(64, 16, 1), 256, 0, stream>>>(
            xn, wcv, 2048, FFD, FFD, nullptr, hb, 1);
        wconv_kernel<<<8192, 256, 0, stream>>>(
            f2_res + (size_t)l * 1024 * 8192, f2_off + (size_t)l * 1024 * 8192,
            wcv, 1024 * 8192);
        gemm_kernel<<<dim3(16, 16, 4), 256, 0, stream>>>(
            hb, wcv, 8192, DM, DM, out, nullptr, 3);   // split-K partials in d_out
        red_kernel<<<4096, 256, 0, stream>>>(xw, out);
    }
    ln_kernel<<<2048, 256, 0, stream>>>(xw, ln_w, ln_b, xn);
    for (int half = 0; half < 2; half++) {
        const float* src = half ? o_off : o_res;
        wconv_kernel<<<8192, 256, 0, stream>>>(src, src, wcv, 8192 * 2048);
        gemm_kernel<<<dim3(64, 16, 1), 256, 0, stream>>>(
            xn, wcv, 2048, 8192, VOC, out + half * 8192, nullptr, 3);
    }
    softmax_kernel<<<2048, 256, 0, stream>>>(out);
}